// Round 5
// baseline (19.330 us; speedup 1.0000x reference)
//
#include <hip/hip_runtime.h>

// Masked normalized cross-correlation, b=8, c=1, H=W=128, p=9.
// R4: intra-block double-buffered mask staging. R1/R3 invariance (~17 us)
// diagnosed as phase-lock: co-resident blocks all stage (DS idle) then all
// compute (HBM idle); barrier re-syncs every generation. Here each block
// covers 64 patches in 2 chunks of 32; chunk k+1's global_load_lds is
// issued right after the barrier and flies under chunk k's compute.
// 4 lanes/patch, row split {0,1},{2,3},{4,5},{6,7,8} (elem = 18h+t so
// r,c stay compile-time). x-slab staged once (row stride 72 / 68-padded).

#define BATCH 8
#define HH    128
#define WW    128
#define PP    9
#define HP    120
#define WP    120
#define NPATCH (HP * WP)        // 14400
#define PSQ   (PP * PP)         // 81
#define EPSF  1e-5f
#define NBLK  (BATCH * HP * 2)  // 1920

__device__ __forceinline__ void gload16(const void* g, void* lds) {
    __builtin_amdgcn_global_load_lds(
        (const __attribute__((address_space(1))) void*)g,
        (__attribute__((address_space(3))) void*)lds, 16, 0, 0);
}

__global__ __launch_bounds__(128) void ncc_kernel(const float* __restrict__ x1,
                                                  const float* __restrict__ x2,
                                                  const float* __restrict__ mask,
                                                  float* __restrict__ part)
{
    const int blk  = blockIdx.x;          // 0 .. 1919
    const int b    = blk / 240;
    const int rest = blk - b * 240;
    const int i    = rest >> 1;           // patch row 0..119
    const int half = rest & 1;
    const int j0   = half << 6;           // 0 or 64
    const int tid  = threadIdx.x;
    const int lane = tid & 63;

    const int RW  = half ? 68 : 72;       // x_lds row stride (floats)
    const int NW4 = half ? 17 : 18;       // staged float4 per row

    __shared__ __align__(16) float m_lds[2][32 * PSQ];  // 2*2592 f = 20736 B
    __shared__ __align__(16) float x_lds[2][9 * 72];    // 2*648 f  =  5184 B
    __shared__ float wsum[2];

    // ---- issue x1/x2 slab stage: rows i..i+8, cols j0..j0+RW-1 ----
    {
        char* d1 = (char*)&x_lds[0][0];
        char* d2 = (char*)&x_lds[1][0];
        #pragma unroll
        for (int k = 0; k < 2; ++k) {
            int t = k * 128 + tid;
            if (t < 9 * NW4) {
                int r, c4;
                if (half) { r = t / 17; c4 = t - r * 17; }
                else      { r = t / 18; c4 = t - r * 18; }
                int sc4 = (half && c4 > 15) ? 15 : c4;   // pad col: reload 60..63, never read
                const size_t rowf = ((size_t)(b * HH + i + r)) * WW + j0;
                gload16(x1 + rowf + sc4 * 4, d1 + (size_t)(t - lane) * 16);
                gload16(x2 + rowf + sc4 * 4, d2 + (size_t)(t - lane) * 16);
            }
        }
    }

    // ---- mask chunk stager (chunk cb: patches j0+32cb .. +npat) ----
    auto stage_mask = [&](int cb) {
        const int cnt4 = ((half && cb) ? 24 : 32) * PSQ / 4;   // 486 or 648
        const float4* msrc = (const float4*)(
            mask + ((size_t)b * NPATCH + (size_t)i * WP + j0 + 32 * cb) * PSQ);
        char* mdst = (char*)&m_lds[cb][0];
        #pragma unroll
        for (int k = 0; k < 6; ++k) {
            int t = k * 128 + tid;
            if (t < cnt4)
                gload16(msrc + t, mdst + (size_t)(t - lane) * 16);
        }
    };

    stage_mask(0);

    float val = 0.0f;
    #pragma unroll
    for (int cb = 0; cb < 2; ++cb) {
        __syncthreads();                 // vmcnt(0) drain: buf cb (and x) ready
        if (cb == 0) stage_mask(1);      // prefetch chunk 1 under compute(0)

        const int npat = (half && cb) ? 24 : 32;
        const int pl   = tid >> 2;       // local patch 0..31
        const int h    = tid & 3;        // row-group
        if (pl < npat) {
            float sa = 0.f, saa = 0.f, sb = 0.f, sbb = 0.f, sab = 0.f;
            const float* mp = &m_lds[cb][pl * PSQ + 18 * h];
            const int col = 32 * cb + pl;            // j - j0
            const float* xa = &x_lds[0][2 * h * RW + col];
            const float* xb = &x_lds[1][2 * h * RW + col];
            #pragma unroll
            for (int t = 0; t < 18; ++t) {           // rows 2h, 2h+1
                const int tr = t / 9, c = t - 9 * tr;
                float a  = xa[tr * RW + c];
                float bv = xb[tr * RW + c] * mp[t];
                sa += a;  saa = fmaf(a, a, saa);
                sb += bv; sbb = fmaf(bv, bv, sbb);
                sab = fmaf(a, bv, sab);
            }
            if (h == 3) {                            // row 8 (elems 54..80 -> t 18..26)
                #pragma unroll
                for (int t = 18; t < 27; ++t) {
                    const int c = t - 18;
                    float a  = xa[2 * RW + c];
                    float bv = xb[2 * RW + c] * mp[t];
                    sa += a;  saa = fmaf(a, a, saa);
                    sb += bv; sbb = fmaf(bv, bv, sbb);
                    sab = fmaf(a, bv, sab);
                }
            }
            // combine 4 lanes of this patch
            sa  += __shfl_xor(sa, 1);  sa  += __shfl_xor(sa, 2);
            saa += __shfl_xor(saa, 1); saa += __shfl_xor(saa, 2);
            sb  += __shfl_xor(sb, 1);  sb  += __shfl_xor(sb, 2);
            sbb += __shfl_xor(sbb, 1); sbb += __shfl_xor(sbb, 2);
            sab += __shfl_xor(sab, 1); sab += __shfl_xor(sab, 2);
            if (h == 0) {
                const float invN = 1.0f / 81.0f;
                float mua  = sa * invN;
                float mub  = sb * invN;
                float vara = saa * invN - mua * mua + EPSF;
                float varb = sbb * invN - mub * mub + EPSF;
                float cov  = sab - 81.0f * mua * mub;
                val += cov / sqrtf(vara * varb);
            }
        }
    }

    // ---- block reduction (2 waves) -> one plain store ----
    #pragma unroll
    for (int off = 32; off > 0; off >>= 1)
        val += __shfl_down(val, off);
    if ((tid & 63) == 0) wsum[tid >> 6] = val;
    __syncthreads();
    if (tid == 0)
        part[blk] = wsum[0] + wsum[1];
}

__global__ __launch_bounds__(256) void finalize_kernel(const float* __restrict__ part,
                                                       float* __restrict__ out)
{
    const int b = blockIdx.x;       // 0..7
    const int t = threadIdx.x;      // 0..255
    float v = (t < 240) ? part[b * 240 + t] : 0.0f;
    #pragma unroll
    for (int off = 32; off > 0; off >>= 1)
        v += __shfl_down(v, off);
    __shared__ float s[4];
    if ((t & 63) == 0) s[t >> 6] = v;
    __syncthreads();
    if (t == 0)
        out[b] = (s[0] + s[1] + s[2] + s[3]) * (1.0f / ((float)NPATCH * (float)PSQ));
}

extern "C" void kernel_launch(void* const* d_in, const int* in_sizes, int n_in,
                              void* d_out, int out_size, void* d_ws, size_t ws_size,
                              hipStream_t stream) {
    const float* x1   = (const float*)d_in[0];
    const float* x2   = (const float*)d_in[1];
    const float* mask = (const float*)d_in[2];
    float* out  = (float*)d_out;
    float* part = (float*)d_ws;     // 1920 floats of scratch

    ncc_kernel<<<NBLK, 128, 0, stream>>>(x1, x2, mask, part);
    finalize_kernel<<<BATCH, 256, 0, stream>>>(part, out);
}

// Round 6
// 19.163 us; speedup vs baseline: 1.0087x; 1.0087x over previous
//
#include <hip/hip_runtime.h>

// Masked normalized cross-correlation, b=8, c=1, H=W=128, p=9.
// R5: deep intra-block pipeline. 480 blocks x 128 threads; each block owns
// (batch, 2 patch-rows). x1/x2 rows i0..i0+9 staged once (full 128-wide,
// stride 128 -> 2-way bank = free). Mask in 4 chunks x 60 patches,
// double-buffered via global_load_lds: stage(k+1) issued right after the
// barrier, flies under compute(k) -> 3/4 of mask HBM latency hidden.
// Compute = R3's verified 2-lane/patch split (rows 0-4 / 5-8), mask stride
// 81 (17*pl mod 32 permutation -> 2-way free). Partials -> ws; single-wave
// finalize kernel.

#define BATCH 8
#define HH    128
#define WW    128
#define PP    9
#define HP    120
#define WP    120
#define NPATCH (HP * WP)        // 14400
#define PSQ   (PP * PP)         // 81
#define EPSF  1e-5f
#define CHUNKP 60               // patches per chunk
#define CHUNKF (CHUNKP * PSQ)   // 4860 floats
#define NBLK  (BATCH * HP / 2)  // 480

__device__ __forceinline__ void gload16(const void* g, void* lds) {
    __builtin_amdgcn_global_load_lds(
        (const __attribute__((address_space(1))) void*)g,
        (__attribute__((address_space(3))) void*)lds, 16, 0, 0);
}

__global__ __launch_bounds__(128) void ncc_kernel(const float* __restrict__ x1,
                                                  const float* __restrict__ x2,
                                                  const float* __restrict__ mask,
                                                  float* __restrict__ part)
{
    const int blk  = blockIdx.x;          // 0..479
    const int b    = blk / 60;
    const int i0   = (blk - b * 60) * 2;  // patch rows i0, i0+1
    const int tid  = threadIdx.x;
    const int lane = tid & 63;

    __shared__ __align__(16) float m_lds[2][CHUNKF];   // 2*19440 B
    __shared__ __align__(16) float x_lds[2][10 * WW];  // 2*5120 B
    __shared__ float wsum[2];

    // ---- stage x1/x2 rows i0..i0+9, full width (320 float4 each) ----
    {
        const float4* s1 = (const float4*)(x1 + ((size_t)(b * HH + i0)) * WW);
        const float4* s2 = (const float4*)(x2 + ((size_t)(b * HH + i0)) * WW);
        char* d1 = (char*)&x_lds[0][0];
        char* d2 = (char*)&x_lds[1][0];
        #pragma unroll
        for (int k = 0; k < 3; ++k) {
            int t = k * 128 + tid;
            if (t < 320) {
                gload16(s1 + t, d1 + (size_t)(t - lane) * 16);
                gload16(s2 + t, d2 + (size_t)(t - lane) * 16);
            }
        }
    }

    // ---- mask chunk stager: chunk k = (row i0 + k/2, half k&1) ----
    auto stage_mask = [&](int k) {
        const int row = i0 + (k >> 1);
        const int jh  = k & 1;
        const float4* msrc = (const float4*)(
            mask + ((size_t)b * NPATCH + (size_t)row * WP + CHUNKP * jh) * PSQ);
        char* mdst = (char*)&m_lds[k & 1][0];
        #pragma unroll
        for (int q = 0; q < 10; ++q) {
            int t = q * 128 + tid;
            if (t < CHUNKF / 4)                        // 1215
                gload16(msrc + t, mdst + (size_t)(t - lane) * 16);
        }
    };

    stage_mask(0);

    float val = 0.0f;
    #pragma unroll
    for (int k = 0; k < 4; ++k) {
        __syncthreads();                 // drains vmcnt: buf k&1 (and x) ready
        if (k < 3) stage_mask(k + 1);    // prefetch under compute(k)

        const int pl = tid >> 1;         // local patch 0..59
        const int h  = tid & 1;
        if (pl < CHUNKP) {
            const int r2 = k >> 1;                     // row offset in slab
            const int j  = CHUNKP * (k & 1) + pl;      // patch column 0..119
            const int rr0 = h ? 5 : 0;
            const int rr1 = h ? 9 : 5;
            float sa = 0.f, saa = 0.f, sb = 0.f, sbb = 0.f, sab = 0.f;
            const float* mp = &m_lds[k & 1][pl * PSQ + rr0 * PP];
            for (int r = rr0; r < rr1; ++r) {
                const float* x1r = &x_lds[0][(r2 + r) * WW + j];
                const float* x2r = &x_lds[1][(r2 + r) * WW + j];
                #pragma unroll
                for (int cc = 0; cc < PP; ++cc) {
                    float a  = x1r[cc];
                    float bv = x2r[cc] * mp[cc];
                    sa += a;  saa = fmaf(a, a, saa);
                    sb += bv; sbb = fmaf(bv, bv, sbb);
                    sab = fmaf(a, bv, sab);
                }
                mp += PP;
            }
            sa  += __shfl_xor(sa, 1);
            saa += __shfl_xor(saa, 1);
            sb  += __shfl_xor(sb, 1);
            sbb += __shfl_xor(sbb, 1);
            sab += __shfl_xor(sab, 1);
            if (h == 0) {
                const float invN = 1.0f / 81.0f;
                float mua  = sa * invN;
                float mub  = sb * invN;
                float vara = saa * invN - mua * mua + EPSF;
                float varb = sbb * invN - mub * mub + EPSF;
                float cov  = sab - 81.0f * mua * mub;
                val += cov / sqrtf(vara * varb);
            }
        }
    }

    // ---- block reduction (2 waves) -> one plain store ----
    #pragma unroll
    for (int off = 32; off > 0; off >>= 1)
        val += __shfl_down(val, off);
    if ((tid & 63) == 0) wsum[tid >> 6] = val;
    __syncthreads();
    if (tid == 0)
        part[blk] = wsum[0] + wsum[1];
}

__global__ __launch_bounds__(64) void finalize_kernel(const float* __restrict__ part,
                                                      float* __restrict__ out)
{
    const int b = blockIdx.x;       // 0..7
    const int t = threadIdx.x;      // 0..63
    float v = (t < 60) ? part[b * 60 + t] : 0.0f;
    #pragma unroll
    for (int off = 32; off > 0; off >>= 1)
        v += __shfl_down(v, off);
    if (t == 0)
        out[b] = v * (1.0f / ((float)NPATCH * (float)PSQ));
}

extern "C" void kernel_launch(void* const* d_in, const int* in_sizes, int n_in,
                              void* d_out, int out_size, void* d_ws, size_t ws_size,
                              hipStream_t stream) {
    const float* x1   = (const float*)d_in[0];
    const float* x2   = (const float*)d_in[1];
    const float* mask = (const float*)d_in[2];
    float* out  = (float*)d_out;
    float* part = (float*)d_ws;     // 480 floats of scratch

    ncc_kernel<<<NBLK, 128, 0, stream>>>(x1, x2, mask, part);
    finalize_kernel<<<BATCH, 64, 0, stream>>>(part, out);
}